// Round 6
// baseline (1006.949 us; speedup 1.0000x reference)
//
#include <hip/hip_runtime.h>
#include <hip/hip_bf16.h>
#include <stdint.h>

// Problem constants (from reference)
#define V_SZ 32000
#define D_SZ 1024          // = K
#define M_SZ 8192          // B*S = 4*2048

typedef __attribute__((ext_vector_type(8))) short bf16x8;
typedef __attribute__((ext_vector_type(4))) float f32x4;
typedef __attribute__((ext_vector_type(16))) float f32x16;

static __device__ __forceinline__ unsigned short f32_to_bf16_rne(float f) {
    union { float f; uint32_t u; } v; v.f = f;
    uint32_t u = v.u;
    uint32_t lsb = (u >> 16) & 1;
    u += 0x7fffu + lsb;
    return (unsigned short)(u >> 16);
}

// ---------------------------------------------------------------------------
// Kernel 1: embedding gather. One block per output row, float4 copy.
__global__ void gather_rows(const int* __restrict__ ids,
                            const float* __restrict__ table,
                            float* __restrict__ out) {
    int row = blockIdx.x;
    int id  = ids[row];
    const f32x4* src = (const f32x4*)(table + (size_t)id * D_SZ);
    f32x4*       dst = (f32x4*)(out + (size_t)row * D_SZ);
    __builtin_nontemporal_store(src[threadIdx.x], &dst[threadIdx.x]);
}

// ---------------------------------------------------------------------------
// Kernel 2: cast embeds f32 -> bf16 (A matrix [M][K]), 8 elems/thread.
__global__ void cast_f32_bf16(const float* __restrict__ in,
                              unsigned short* __restrict__ out, int n8) {
    int i = blockIdx.x * blockDim.x + threadIdx.x;
    int stride = gridDim.x * blockDim.x;
    for (; i < n8; i += stride) {
        const float4* p = (const float4*)(in + (size_t)i * 8);
        float4 a = p[0], b = p[1];
        union { unsigned short s[8]; uint4 v; } r;
        r.s[0] = f32_to_bf16_rne(a.x); r.s[1] = f32_to_bf16_rne(a.y);
        r.s[2] = f32_to_bf16_rne(a.z); r.s[3] = f32_to_bf16_rne(a.w);
        r.s[4] = f32_to_bf16_rne(b.x); r.s[5] = f32_to_bf16_rne(b.y);
        r.s[6] = f32_to_bf16_rne(b.z); r.s[7] = f32_to_bf16_rne(b.w);
        ((uint4*)out)[i] = r.v;
    }
}

// ---------------------------------------------------------------------------
// Kernel 3: transpose+cast out_weight [K=1024][V=32000] f32 -> Bt [V][K] bf16.
__global__ void transpose_cast(const float* __restrict__ w,
                               unsigned short* __restrict__ bt) {
    __shared__ unsigned short tile[32][34];
    int n0 = blockIdx.x * 32;          // column block in V
    int k0 = blockIdx.y * 32;          // row block in K
    int r = threadIdx.x >> 5;          // 0..7
    int c = threadIdx.x & 31;          // 0..31
#pragma unroll
    for (int rr = 0; rr < 32; rr += 8) {
        float v = w[(size_t)(k0 + r + rr) * V_SZ + (n0 + c)];
        tile[c][r + rr] = f32_to_bf16_rne(v);
    }
    __syncthreads();
    int nl = threadIdx.x >> 3;         // 0..31
    int ks = threadIdx.x & 7;          // 0..7  (4 bf16 = 8B per thread)
    union { unsigned short s[4]; uint2 v; } r2;
#pragma unroll
    for (int j = 0; j < 4; ++j) r2.s[j] = tile[nl][ks * 4 + j];
    ((uint2*)(bt + (size_t)(n0 + nl) * D_SZ + k0))[ks] = r2.v;
}

// ---------------------------------------------------------------------------
// Kernel 4: bf16 GEMM, 128x128 tile, BK=64, 4 waves (2Mx2N), 2-phase/K-tile,
// 32x32x16 MFMA, double-buffered 64 KiB LDS -> *2 blocks per CU* so the
// barrier bubbles / prologue / epilogue of one block overlap the other
// block's MFMA (K=1024 makes the per-block ends ~1/3 of block time).
// k-split LDS layout (0 conflicts measured). Counted vmcnt(4) per tile.
// XCD mapping: an XCD's 64 resident blocks share 1 B panel (256 KB) and a
// pinned 2 MB A slice -> L2 working set ~2.3 MB; XCDs sweep bn in lockstep
// so L3 serves each B panel ~once.
#define BM 128
#define BN 128
#define BK 64
#define NT (D_SZ / BK)   // 16

static __device__ __forceinline__ void gload_lds16(const unsigned short* g, void* lds) {
    __builtin_amdgcn_global_load_lds(
        (const __attribute__((address_space(1))) void*)g,
        (__attribute__((address_space(3))) void*)lds,
        16, 0, 0);
}

__global__ __launch_bounds__(256, 2)
void gemm_bf16_2b(const unsigned short* __restrict__ A,
                  const unsigned short* __restrict__ Bt,
                  float* __restrict__ C) {
    __shared__ __align__(16) char lds[65536];   // [dbuf][A|B][8 hi][128 row][16B]

    const int tid  = threadIdx.x;
    const int lane = tid & 63;
    const int w    = tid >> 6;           // wave 0..3
    const int wr   = w >> 1;             // 0..1  (M half)
    const int wc   = w & 1;              // 0..1  (N half)

    // bid = (j<<3)|xcd ; xcd owns bm tiles [8*xcd, 8*xcd+7] (2 MB A slice);
    // all XCDs process the same bn concurrently (64 consecutive bids = 1 bn).
    const int bid = blockIdx.x;
    const int xcd = bid & 7;
    const int j   = bid >> 3;            // 0..1999
    const int bm0 = (xcd * 8 + (j & 7)) * BM;   // 64 bm tiles
    const int bn0 = (j >> 3) * BN;              // 250 bn tiles

    // staging map: thread covers (hi0 + 2k, row0), k=0..3  (4 x 16B per stage)
    const int hi0  = tid >> 7;           // 0..1
    const int row0 = tid & 127;          // 0..127
    const int dstO = hi0 * 2048 + row0 * 16;
    const unsigned short* gA = A  + (size_t)(bm0 + row0) * D_SZ + hi0 * 8;
    const unsigned short* gB = Bt + (size_t)(bn0 + row0) * D_SZ + hi0 * 8;

#define STG_A(tt, db) { _Pragma("unroll") for (int k_ = 0; k_ < 4; ++k_) \
    gload_lds16(gA + (tt) * 64 + k_ * 16, (char*)lds + (db) + dstO + k_ * 4096); }
#define STG_B(tt, db) { _Pragma("unroll") for (int k_ = 0; k_ < 4; ++k_) \
    gload_lds16(gB + (tt) * 64 + k_ * 16, (char*)lds + (db) + 16384 + dstO + k_ * 4096); }

    // Prologue: A(0),B(0) -> buf0; A(1) -> buf1.  (B(1) staged in P0 of t=0.)
    STG_A(0, 0); STG_B(0, 0); STG_A(1, 32768);
    asm volatile("s_waitcnt vmcnt(4)" ::: "memory");   // A(0),B(0) landed
    __builtin_amdgcn_s_barrier();

    f32x16 acc[2][2];
#pragma unroll
    for (int g = 0; g < 2; ++g)
#pragma unroll
        for (int n = 0; n < 2; ++n)
#pragma unroll
            for (int e = 0; e < 16; ++e) acc[g][n][e] = 0.0f;

    bf16x8 a[2][4];   // [g][kk]  A frags for both 32-row groups, full K-tile
    bf16x8 b[4];      // [kk]     B frags for current n-quadrant

    // 32x32x16 frag: row/col = lane&31, k-group = kk*2 + (lane>>5)
    const int base_f = (lane >> 5) * 2048 + (lane & 31) * 16;

#define LDA(g, kk) (*(const bf16x8*)(abuf + (kk) * 4096 + (g) * 512 + base_f))
#define LDB(n, kk) (*(const bf16x8*)(bbuf + (kk) * 4096 + (n) * 512 + base_f))

#define MFMA_N(N) \
    __builtin_amdgcn_s_setprio(1); \
    _Pragma("unroll") for (int kk = 0; kk < 4; ++kk) \
    _Pragma("unroll") for (int g = 0; g < 2; ++g) \
        acc[g][N] = __builtin_amdgcn_mfma_f32_32x32x16_bf16( \
            a[g][kk], b[kk], acc[g][N], 0, 0, 0); \
    __builtin_amdgcn_s_setprio(0);

    for (int t = 0; t < NT; ++t) {
        const int   dbuf  = (t & 1) * 32768;
        const int   ndbuf = dbuf ^ 32768;
        const char* abuf  = (const char*)lds + dbuf + wr * 1024;
        const char* bbuf  = (const char*)lds + dbuf + 16384 + wc * 1024;

        // ---- P0: a(g0,g1) + b(n0); stage B(t+1) -> ndbuf (its readers done
        //      at tile t-1's trailing barrier).
        a[0][0] = LDA(0, 0); a[0][1] = LDA(0, 1); a[0][2] = LDA(0, 2); a[0][3] = LDA(0, 3);
        a[1][0] = LDA(1, 0); a[1][1] = LDA(1, 1); a[1][2] = LDA(1, 2); a[1][3] = LDA(1, 3);
        b[0] = LDB(0, 0); b[1] = LDB(0, 1); b[2] = LDB(0, 2); b[3] = LDB(0, 3);
        if (t + 1 < NT) STG_B(t + 1, ndbuf);
        __builtin_amdgcn_sched_barrier(0);
        __builtin_amdgcn_s_barrier();
        MFMA_N(0);
        __builtin_amdgcn_s_barrier();

        // ---- P1: b(n1); stage A(t+2) -> dbuf (A(dbuf) reads completed
        //      before P0's trailing barrier).
        b[0] = LDB(1, 0); b[1] = LDB(1, 1); b[2] = LDB(1, 2); b[3] = LDB(1, 3);
        if (t + 2 < NT) STG_A(t + 2, dbuf);
        __builtin_amdgcn_sched_barrier(0);
        __builtin_amdgcn_s_barrier();
        MFMA_N(1);
        // counted wait: exactly tile t+1's 8 loads guaranteed landed
        if (t < NT - 2)       { asm volatile("s_waitcnt vmcnt(4)" ::: "memory"); }
        else if (t == NT - 2) { asm volatile("s_waitcnt vmcnt(0)" ::: "memory"); }
        __builtin_amdgcn_s_barrier();
    }

    // Epilogue. 32x32 C frag: col = lane&31, row = (r&3) + 8*(r>>2) + 4*(lane>>5).
    const int crow = bm0 + wr * 64 + (lane >> 5) * 4;
    const int ccol = bn0 + wc * 64 + (lane & 31);
#pragma unroll
    for (int g = 0; g < 2; ++g)
#pragma unroll
        for (int n = 0; n < 2; ++n) {
            float* base = C + (size_t)(crow + g * 32) * V_SZ + (ccol + n * 32);
#pragma unroll
            for (int r = 0; r < 16; ++r) {
                int roff = (r & 3) + 8 * (r >> 2);
                __builtin_nontemporal_store(acc[g][n][r], base + (size_t)roff * V_SZ);
            }
        }
#undef STG_A
#undef STG_B
#undef LDA
#undef LDB
#undef MFMA_N
}

// ---------------------------------------------------------------------------
extern "C" void kernel_launch(void* const* d_in, const int* in_sizes, int n_in,
                              void* d_out, int out_size, void* d_ws, size_t ws_size,
                              hipStream_t stream) {
    const int*   ids        = (const int*)d_in[0];       // [B,S] = 8192
    const float* embeds     = (const float*)d_in[1];     // [B,S,D]
    const float* in_weight  = (const float*)d_in[2];     // [V,D]
    const float* out_weight = (const float*)d_in[3];     // [D,V]

    float* out_embedded = (float*)d_out;                       // M*D floats
    float* out_logits   = (float*)d_out + (size_t)M_SZ * D_SZ; // M*V floats

    // workspace: A bf16 [M][K] (16 MB) + Bt bf16 [V][K] (64 MB) = ~82 MB
    unsigned short* Abf  = (unsigned short*)d_ws;
    unsigned short* Btbf = Abf + (size_t)M_SZ * D_SZ;

    gather_rows<<<M_SZ, 256, 0, stream>>>(ids, in_weight, out_embedded);
    cast_f32_bf16<<<2048, 256, 0, stream>>>(embeds, Abf, M_SZ * D_SZ / 8);
    transpose_cast<<<dim3(V_SZ / 32, D_SZ / 32), 256, 0, stream>>>(out_weight, Btbf);
    gemm_bf16_2b<<<dim3((V_SZ / BN) * (M_SZ / BM)), 256, 0, stream>>>(Abf, Btbf, out_logits);
}

// Round 8
// 676.734 us; speedup vs baseline: 1.4880x; 1.4880x over previous
//
#include <hip/hip_runtime.h>
#include <hip/hip_bf16.h>
#include <stdint.h>

// Problem constants (from reference)
#define V_SZ 32000
#define D_SZ 1024          // = K
#define M_SZ 8192          // B*S = 4*2048

typedef __attribute__((ext_vector_type(8))) short bf16x8;
typedef __attribute__((ext_vector_type(4))) float f32x4;
typedef __attribute__((ext_vector_type(16))) float f32x16;

static __device__ __forceinline__ unsigned short f32_to_bf16_rne(float f) {
    union { float f; uint32_t u; } v; v.f = f;
    uint32_t u = v.u;
    uint32_t lsb = (u >> 16) & 1;
    u += 0x7fffu + lsb;
    return (unsigned short)(u >> 16);
}

// ---------------------------------------------------------------------------
// Kernel 1: embedding gather. One block per output row, float4 copy.
__global__ void gather_rows(const int* __restrict__ ids,
                            const float* __restrict__ table,
                            float* __restrict__ out) {
    int row = blockIdx.x;
    int id  = ids[row];
    const f32x4* src = (const f32x4*)(table + (size_t)id * D_SZ);
    f32x4*       dst = (f32x4*)(out + (size_t)row * D_SZ);
    __builtin_nontemporal_store(src[threadIdx.x], &dst[threadIdx.x]);
}

// ---------------------------------------------------------------------------
// Kernel 2: cast embeds f32 -> bf16 (A matrix [M][K]), 8 elems/thread.
__global__ void cast_f32_bf16(const float* __restrict__ in,
                              unsigned short* __restrict__ out, int n8) {
    int i = blockIdx.x * blockDim.x + threadIdx.x;
    int stride = gridDim.x * blockDim.x;
    for (; i < n8; i += stride) {
        const float4* p = (const float4*)(in + (size_t)i * 8);
        float4 a = p[0], b = p[1];
        union { unsigned short s[8]; uint4 v; } r;
        r.s[0] = f32_to_bf16_rne(a.x); r.s[1] = f32_to_bf16_rne(a.y);
        r.s[2] = f32_to_bf16_rne(a.z); r.s[3] = f32_to_bf16_rne(a.w);
        r.s[4] = f32_to_bf16_rne(b.x); r.s[5] = f32_to_bf16_rne(b.y);
        r.s[6] = f32_to_bf16_rne(b.z); r.s[7] = f32_to_bf16_rne(b.w);
        ((uint4*)out)[i] = r.v;
    }
}

// ---------------------------------------------------------------------------
// Kernel 3: transpose+cast out_weight [K=1024][V=32000] f32 -> Bt [V][K] bf16.
__global__ void transpose_cast(const float* __restrict__ w,
                               unsigned short* __restrict__ bt) {
    __shared__ unsigned short tile[32][34];
    int n0 = blockIdx.x * 32;          // column block in V
    int k0 = blockIdx.y * 32;          // row block in K
    int r = threadIdx.x >> 5;          // 0..7
    int c = threadIdx.x & 31;          // 0..31
#pragma unroll
    for (int rr = 0; rr < 32; rr += 8) {
        float v = w[(size_t)(k0 + r + rr) * V_SZ + (n0 + c)];
        tile[c][r + rr] = f32_to_bf16_rne(v);
    }
    __syncthreads();
    int nl = threadIdx.x >> 3;         // 0..31
    int ks = threadIdx.x & 7;          // 0..7  (4 bf16 = 8B per thread)
    union { unsigned short s[4]; uint2 v; } r2;
#pragma unroll
    for (int j = 0; j < 4; ++j) r2.s[j] = tile[nl][ks * 4 + j];
    ((uint2*)(bt + (size_t)(n0 + nl) * D_SZ + k0))[ks] = r2.v;
}

// ---------------------------------------------------------------------------
// Kernel 4: PERSISTENT bf16 GEMM. 256 blocks (1/CU), each owns a fixed bm
// panel (A pointers loop-invariant; A staging wraps mod 16) and sweeps 15-16
// bn tiles. The 4-phase counted-vmcnt pipeline runs continuously across tile
// boundaries (t=14/15 stage next tile's steps 0/1), so there is no per-tile
// prologue stall or drain; the C epilogue overlaps in-flight staging.
// 256x256 tile, BK=64, 8 waves (2Mx4N), 32x32x16 MFMA, 128 KiB LDS dbuf,
// k-split layout (0 bank conflicts measured rounds 1-6).
// BUGFIX r7: loop-staged A1 half-tile was missing the +128*D_SZ row offset
// (stages rows 128-255, not rows 0-127) -- caused absmax 258.
#define BM 256
#define BN 256
#define BK 64
#define NSTEP (D_SZ / BK)   // 16 K-steps per tile

static __device__ __forceinline__ void gload_lds16(const unsigned short* g, void* lds) {
    __builtin_amdgcn_global_load_lds(
        (const __attribute__((address_space(1))) void*)g,
        (__attribute__((address_space(3))) void*)lds,
        16, 0, 0);
}

__global__ __launch_bounds__(512, 2)
void gemm_persist(const unsigned short* __restrict__ A,
                  const unsigned short* __restrict__ Bt,
                  float* __restrict__ C) {
    __shared__ __align__(16) char lds[131072];

    const int tid  = threadIdx.x;
    const int lane = tid & 63;
    const int w    = tid >> 6;           // wave 0..7
    const int wr   = w >> 2;             // 0..1  (A half)
    const int wc   = w & 3;              // 0..3  (B: half = wc>>1, sub = wc&1)

    // bid&7 = XCD. Block keeps bm fixed: bm = xcd*4 + (jb&3) (2 MB A slice /
    // XCD, L2-pinned). bn tile index = q0 + 8r -> all XCDs sweep the same bn
    // octet at the same r (L3 lockstep). Bijective over 4000 tiles:
    // q0<=4 (bid<160) does 16 tiles, q0>=5 does 15.
    const int bid = blockIdx.x;
    const int xcd = bid & 7;
    const int jb  = bid >> 3;            // 0..31
    const int bm0 = (xcd * 4 + (jb & 3)) * BM;
    const int q0  = jb >> 2;             // 0..7
    const int ntiles = (bid < 160) ? 16 : 15;

    // staging thread mapping: (hi0,row0) and (hi0+4,row0)
    const int hi0  = tid >> 7;           // 0..3
    const int row0 = tid & 127;          // 0..127
    const int dstO = hi0 * 2048 + row0 * 16;
    const unsigned short* gA = A  + (size_t)(bm0 + row0) * D_SZ + hi0 * 8;   // invariant
    const unsigned short* gA1 = gA + (size_t)128 * D_SZ;                     // rows 128-255
    const unsigned short* gBc = Bt + (size_t)(q0 * BN + row0) * D_SZ + hi0 * 8;
    const size_t bn_stride = (size_t)8 * BN * D_SZ;   // bn advances 8 tiles per r

#define STG(ptr, slotbase) do { \
    gload_lds16((ptr),      (char*)lds + (slotbase) + dstO); \
    gload_lds16((ptr) + 32, (char*)lds + (slotbase) + dstO + 8192); } while (0)

    // Prologue: tile0 step0 fully + step1 minus A1(1); wait oldest 8.
    STG(gBc,                           32768);
    STG(gBc + (size_t)128 * D_SZ,      32768 + 16384);
    STG(gA,                            0);
    STG(gA1,                           16384);
    STG(gBc + 64,                      65536 + 32768);
    STG(gBc + (size_t)128 * D_SZ + 64, 65536 + 32768 + 16384);
    STG(gA + 64,                       65536);
    asm volatile("s_waitcnt vmcnt(6)" ::: "memory");
    __builtin_amdgcn_s_barrier();

    f32x16 acc[4][2];
#pragma unroll
    for (int m = 0; m < 4; ++m)
#pragma unroll
        for (int n = 0; n < 2; ++n)
#pragma unroll
            for (int e = 0; e < 16; ++e) acc[m][n][e] = 0.0f;

    bf16x8 a[2][4];       // [mi2][kk] current QM quadrant
    bf16x8 b[2][4];       // [qn][kk]  both QN quadrants live

    // 32x32x16 frag: row/col = lane&31, k-group = kk*2 + (lane>>5)
    const int base_f = (lane >> 5) * 2048 + (lane & 31) * 16;

#define LDA(mi2, kk, QM) (*(const bf16x8*)(abuf + (kk) * 4096 + ((QM) * 2 + (mi2)) * 512 + base_f))
#define LDB(ni, kk)      (*(const bf16x8*)(bbuf + (kk) * 4096 + (ni) * 512 + base_f))

#define MFMA_Q(QM, QN) \
    __builtin_amdgcn_s_setprio(1); \
    _Pragma("unroll") for (int kk = 0; kk < 4; ++kk) \
    _Pragma("unroll") for (int mi2 = 0; mi2 < 2; ++mi2) \
        acc[(QM) * 2 + mi2][QN] = __builtin_amdgcn_mfma_f32_32x32x16_bf16( \
            a[mi2][kk], b[QN][kk], acc[(QM) * 2 + mi2][QN], 0, 0, 0); \
    __builtin_amdgcn_s_setprio(0);

#define MIDSYNC \
    __builtin_amdgcn_sched_barrier(0); \
    __builtin_amdgcn_s_barrier();

    const int crow = bm0 + wr * 128 + (lane >> 5) * 4;
    const int ccol_f = wc * 64 + (lane & 31);

    for (int r = 0; r < ntiles; ++r) {
        const unsigned short* gBn = gBc + bn_stride;
        const bool last = (r == ntiles - 1);

        for (int t = 0; t < NSTEP; ++t) {
            const int   dbuf = (t & 1) << 16;
            const char* abuf = (const char*)lds + dbuf + wr * 16384;
            const char* bbuf = (const char*)lds + dbuf + 32768
                               + (wc >> 1) * 16384 + (wc & 1) * 1024;
            const int nslot = (dbuf ^ 65536);

            // ---- P0: (QM0,QN0); stage A1(step t+1) = ROWS 128-255 (gA1!)
            a[0][0] = LDA(0, 0, 0); a[0][1] = LDA(0, 1, 0);
            a[0][2] = LDA(0, 2, 0); a[0][3] = LDA(0, 3, 0);
            a[1][0] = LDA(1, 0, 0); a[1][1] = LDA(1, 1, 0);
            a[1][2] = LDA(1, 2, 0); a[1][3] = LDA(1, 3, 0);
            b[0][0] = LDB(0, 0); b[0][1] = LDB(0, 1);
            b[0][2] = LDB(0, 2); b[0][3] = LDB(0, 3);
            if (!(last && t == 15)) STG(gA1 + ((t + 1) & 15) * 64, nslot + 16384);
            MIDSYNC;
            MFMA_Q(0, 0);
            __builtin_amdgcn_s_barrier();

            // ---- P1: (QM0,QN1)
            b[1][0] = LDB(1, 0); b[1][1] = LDB(1, 1);
            b[1][2] = LDB(1, 2); b[1][3] = LDB(1, 3);
            MIDSYNC;
            MFMA_Q(0, 1);
            __builtin_amdgcn_s_barrier();

            // ---- P2: (QM1,QN1); stage B0(step t+2) (next tile when t>=14)
            a[0][0] = LDA(0, 0, 1); a[0][1] = LDA(0, 1, 1);
            a[0][2] = LDA(0, 2, 1); a[0][3] = LDA(0, 3, 1);
            a[1][0] = LDA(1, 0, 1); a[1][1] = LDA(1, 1, 1);
            a[1][2] = LDA(1, 2, 1); a[1][3] = LDA(1, 3, 1);
            if (t < 14 || !last) {
                const unsigned short* pb = (t < 14) ? gBc + (t + 2) * 64
                                                    : gBn + (t - 14) * 64;
                STG(pb, dbuf + 32768);
            }
            MIDSYNC;
            MFMA_Q(1, 1);
            __builtin_amdgcn_s_barrier();

            // ---- P3: (QM1,QN0); stage B1(t+2), A0(t+2)
            if (t < 14 || !last) {
                const unsigned short* pb = (t < 14) ? gBc + (t + 2) * 64
                                                    : gBn + (t - 14) * 64;
                STG(pb + (size_t)128 * D_SZ, dbuf + 32768 + 16384);
                STG(gA + ((t + 2) & 15) * 64, dbuf);
            }
            MFMA_Q(1, 0);
            if (last && t >= 14) { asm volatile("s_waitcnt vmcnt(0)" ::: "memory"); }
            else                 { asm volatile("s_waitcnt vmcnt(6)" ::: "memory"); }
            __builtin_amdgcn_s_barrier();
        }

        // Epilogue for tile r (in-flight staging for tile r+1 continues).
        // 32x32 C frag: col = lane&31, row = (e&3) + 8*(e>>2) + 4*(lane>>5).
        const int ccol = (q0 + 8 * r) * BN + ccol_f;
#pragma unroll
        for (int mi = 0; mi < 4; ++mi)
#pragma unroll
            for (int ni = 0; ni < 2; ++ni) {
                float* base = C + (size_t)(crow + mi * 32) * V_SZ + (ccol + ni * 32);
#pragma unroll
                for (int e = 0; e < 16; ++e) {
                    int roff = (e & 3) + 8 * (e >> 2);
                    __builtin_nontemporal_store(acc[mi][ni][e], base + (size_t)roff * V_SZ);
                }
            }
#pragma unroll
        for (int m = 0; m < 4; ++m)
#pragma unroll
            for (int n = 0; n < 2; ++n)
#pragma unroll
                for (int e = 0; e < 16; ++e) acc[m][n][e] = 0.0f;

        gBc = gBn;
    }
#undef STG
#undef LDA
#undef LDB
#undef MFMA_Q
#undef MIDSYNC
}

// ---------------------------------------------------------------------------
extern "C" void kernel_launch(void* const* d_in, const int* in_sizes, int n_in,
                              void* d_out, int out_size, void* d_ws, size_t ws_size,
                              hipStream_t stream) {
    const int*   ids        = (const int*)d_in[0];       // [B,S] = 8192
    const float* embeds     = (const float*)d_in[1];     // [B,S,D]
    const float* in_weight  = (const float*)d_in[2];     // [V,D]
    const float* out_weight = (const float*)d_in[3];     // [D,V]

    float* out_embedded = (float*)d_out;                       // M*D floats
    float* out_logits   = (float*)d_out + (size_t)M_SZ * D_SZ; // M*V floats

    // workspace: A bf16 [M][K] (16 MB) + Bt bf16 [V][K] (64 MB) = ~82 MB
    unsigned short* Abf  = (unsigned short*)d_ws;
    unsigned short* Btbf = Abf + (size_t)M_SZ * D_SZ;

    gather_rows<<<M_SZ, 256, 0, stream>>>(ids, in_weight, out_embedded);
    cast_f32_bf16<<<2048, 256, 0, stream>>>(embeds, Abf, M_SZ * D_SZ / 8);
    transpose_cast<<<dim3(V_SZ / 32, D_SZ / 32), 256, 0, stream>>>(out_weight, Btbf);
    gemm_persist<<<dim3(256), 512, 0, stream>>>(Abf, Btbf, out_logits);
}